// Round 9
// baseline (64.059 us; speedup 1.0000x reference)
//
#include <hip/hip_runtime.h>
#include <hip/hip_fp16.h>

// ROIAlign: input (B=2, C=256, H=200, W=200) f32, rois (R=512, 5) f32
// output (R, C, 7, 7) f32.  sampling_ratio = 2, spatial_scale = 0.0625.
//
// Round 9: revert to round-6 pipeline (G=8, 2-buffer, counted vmcnt(NI),
// roi-major). Occupancy was capped by worst-case LDS (12.8 KB for all
// blocks). Split into two launches by region size T (from header, uniform
// read, early-exit): A: T<=1024 -> 8 KB LDS (20 blocks/CU); B: T>1024 ->
// 12.8 KB (12 blocks/CU). No atomics; deterministic.

#define B_  2
#define C_  256
#define H_  200
#define W_  200
#define R_  512
#define HW_ (H_ * W_)
#define TOTAL_ (B_ * C_ * HW_)
#define G_   8      // channels per wave
#define TSPLIT_ 1024

#define HDR_BYTES_  (R_ * 8 * 4)              // 16384
#define META_BYTES_ (R_ * 4 * 64 * 16)        // 2097152
#define WS_NEED_    (HDR_BYTES_ + META_BYTES_)

typedef __attribute__((address_space(3))) unsigned int lds_u32;
typedef const __attribute__((address_space(1))) unsigned int glb_u32;

__device__ __forceinline__ float sample_coord(float start, float bin, int p, int i) {
    // Single definition shared by bounds and per-sample math: identical fp
    // rounding guarantees relative region indices stay in-bounds.
    return start + (float)p * bin + ((float)i + 0.5f) * bin * 0.5f;
}
__device__ __forceinline__ int lo_clamped(float v, int size) {
    return (int)fminf(floorf(fmaxf(v, 0.0f)), (float)(size - 1));
}
__device__ __forceinline__ unsigned int pack_h2(float a, float b) {
    unsigned short ua = __half_as_ushort(__float2half(a));
    unsigned short ub = __half_as_ushort(__float2half(b));
    return (unsigned int)ua | ((unsigned int)ub << 16);
}
__device__ __forceinline__ float h2f_lo(unsigned int u) {
    return __half2float(__ushort_as_half((unsigned short)(u & 0xffffu)));
}
__device__ __forceinline__ float h2f_hi(unsigned int u) {
    return __half2float(__ushort_as_half((unsigned short)(u >> 16)));
}

// ---------------- meta kernel: one 64-thread block per roi ----------------
__global__ __launch_bounds__(64) void roialign_meta(
    const float* __restrict__ rois, int* __restrict__ hdr, int4* __restrict__ meta) {
    int r = blockIdx.x;
    int lane = threadIdx.x;

    const float scale = 0.0625f;
    float bf = rois[r * 5 + 0];
    int   bi = (int)bf;
    float x1 = rois[r * 5 + 1] * scale;
    float y1 = rois[r * 5 + 2] * scale;
    float x2 = rois[r * 5 + 3] * scale;
    float y2 = rois[r * 5 + 4] * scale;
    float bin_w = fmaxf(x2 - x1, 1.0f) * (1.0f / 7.0f);
    float bin_h = fmaxf(y2 - y1, 1.0f) * (1.0f / 7.0f);

    int y0 = lo_clamped(sample_coord(y1, bin_h, 0, 0), H_);
    int yE = min(lo_clamped(sample_coord(y1, bin_h, 6, 1), H_) + 1, H_ - 1);
    int x0 = lo_clamped(sample_coord(x1, bin_w, 0, 0), W_);
    int xE = min(lo_clamped(sample_coord(x1, bin_w, 6, 1), W_) + 1, W_ - 1);
    int rows = yE - y0 + 1;
    int cols = xE - x0 + 1;
    int cols4 = (cols + 3) & ~3;
    if ((cols4 & 31) == 0) cols4 += 4;   // dodge 32-bank alignment
    int   T = rows * cols4;              // always a multiple of 4
    int   nIter = (T + 255) >> 8;
    float recip = 1.0f / (float)cols4;   // floor((e+0.5)*recip) == e/cols4 exactly

    if (lane == 0) {
        int* h = hdr + r * 8;
        h[0] = y0 * W_ + x0;
        h[1] = bi;
        h[2] = cols4;
        h[3] = T;
        h[4] = __float_as_int(recip);
        h[5] = nIter;
        h[6] = 0;
        h[7] = 0;
    }

    int4 o[4] = {{0,0,0,0},{0,0,0,0},{0,0,0,0},{0,0,0,0}};
    if (lane < 49) {
        int ph = lane / 7;
        int pw = lane % 7;

        int   rlo_b[2], rhi_b[2];
        float fy[2];
        bool  vy[2];
#pragma unroll
        for (int iy = 0; iy < 2; ++iy) {
            float y = sample_coord(y1, bin_h, ph, iy);
            vy[iy] = (y >= -1.0f) && (y <= (float)H_);
            float yc = fmaxf(y, 0.0f);
            float yl = floorf(yc);
            bool  edge = yl >= (float)(H_ - 1);
            int   lo = (int)fminf(yl, (float)(H_ - 1));
            int   hi = min(lo + 1, H_ - 1);
            fy[iy] = edge ? 0.0f : (yc - yl);
            rlo_b[iy] = (lo - y0) * cols4 * 4;   // LDS byte offset
            rhi_b[iy] = (hi - y0) * cols4 * 4;
        }
        int   clo_b[2], chi_b[2];
        float fx[2];
        bool  vx[2];
#pragma unroll
        for (int ix = 0; ix < 2; ++ix) {
            float x = sample_coord(x1, bin_w, pw, ix);
            vx[ix] = (x >= -1.0f) && (x <= (float)W_);
            float xc = fmaxf(x, 0.0f);
            float xl = floorf(xc);
            bool  edge = xl >= (float)(W_ - 1);
            int   lo = (int)fminf(xl, (float)(W_ - 1));
            int   hi = min(lo + 1, W_ - 1);
            fx[ix] = edge ? 0.0f : (xc - xl);
            clo_b[ix] = (lo - x0) * 4;
            chi_b[ix] = (hi - x0) * 4;
        }
#pragma unroll
        for (int iy = 0; iy < 2; ++iy)
#pragma unroll
            for (int ix = 0; ix < 2; ++ix) {
                int s = iy * 2 + ix;
                float mk  = (vy[iy] && vx[ix]) ? 0.25f : 0.0f;  // mask * 1/(S*S)
                float wy0 = (1.0f - fy[iy]) * mk;
                float wy1 = fy[iy] * mk;
                float wx0 = 1.0f - fx[ix];
                float wx1 = fx[ix];
                o[s].x = rlo_b[iy] | (rhi_b[iy] << 16);
                o[s].y = clo_b[ix] | (chi_b[ix] << 16);
                o[s].z = (int)pack_h2(wy0, wy1);
                o[s].w = (int)pack_h2(wx0, wx1);
            }
    }
#pragma unroll
    for (int s = 0; s < 4; ++s)
        meta[((r * 4 + s) * 64) + lane] = o[s];
}

// ---------------- pipelined main kernels ----------------
template<int N> __device__ __forceinline__ void wait_vmcnt() {
    if constexpr (N == 0)      asm volatile("s_waitcnt vmcnt(0)" ::: "memory");
    else if constexpr (N == 1) asm volatile("s_waitcnt vmcnt(1)" ::: "memory");
    else if constexpr (N == 2) asm volatile("s_waitcnt vmcnt(2)" ::: "memory");
    else if constexpr (N == 3) asm volatile("s_waitcnt vmcnt(3)" ::: "memory");
    else if constexpr (N == 4) asm volatile("s_waitcnt vmcnt(4)" ::: "memory");
    else if constexpr (N == 5) asm volatile("s_waitcnt vmcnt(5)" ::: "memory");
    else if constexpr (N == 6) asm volatile("s_waitcnt vmcnt(6)" ::: "memory");
    else                       asm volatile("s_waitcnt vmcnt(7)" ::: "memory");
}

template<int NI>
__device__ __forceinline__ void body(
    const float* __restrict__ input, float* __restrict__ out,
    float* __restrict__ b0, float* __restrict__ b1,
    int lane, int srcbase, int cols4, float recip, int T,
    const int (&off)[16], const float (&wt)[16], int obase) {

    int e4 = lane << 2;

    // Per-lane staging offsets for the NI dwordx4 instructions (advance by
    // HW_ per channel). All indices compile-time after unroll -> registers.
    int so[NI];
#pragma unroll
    for (int i = 0; i < NI; ++i) {
        int e = e4 + (i << 8);
        int row = (int)(((float)e + 0.5f) * recip);
        int col = e - row * cols4;
        so[i] = srcbase + row * W_ + col;
    }

    auto STAGE = [&](float* bp) {
#pragma unroll
        for (int i = 0; i < NI; ++i) {
            if (e4 + (i << 8) < T) {                    // protect LDS buffer end
                int g = min(so[i], TOTAL_ - 4);         // tail-of-input safety
                __builtin_amdgcn_global_load_lds((glb_u32*)(input + g),
                                                 (lds_u32*)(bp + (i << 8)), 16, 0, 0);
            }
            so[i] += HW_;
        }
    };

    STAGE(b0);   // ch 0
    STAGE(b1);   // ch 1

    float accs[G_];
#pragma unroll
    for (int k = 0; k < G_; ++k) {
        // ch k's stage is the oldest NI loads; ch k+1's NI may stay in flight.
        if (k < G_ - 1) wait_vmcnt<NI>(); else wait_vmcnt<0>();
        float* bp = (k & 1) ? b1 : b0;
        const char* bb = (const char*)bp;
        float a = 0.0f;
#pragma unroll
        for (int s = 0; s < 4; ++s) {
            float v1 = *(const float*)(bb + off[4*s+0]);
            float v2 = *(const float*)(bb + off[4*s+1]);
            float v3 = *(const float*)(bb + off[4*s+2]);
            float v4 = *(const float*)(bb + off[4*s+3]);
            a += wt[4*s+0] * (wt[4*s+2] * v1 + wt[4*s+3] * v2)
               + wt[4*s+1] * (wt[4*s+2] * v3 + wt[4*s+3] * v4);
        }
        accs[k] = a;
        if (k < G_ - 2) {
            // All ds_reads from bp must have completed before overwriting it.
            asm volatile("s_waitcnt lgkmcnt(0)" ::: "memory");
            __builtin_amdgcn_sched_barrier(0);
            STAGE(bp);                                   // ch k+2, same buffer
        }
    }

    if (lane < 49) {
#pragma unroll
        for (int k = 0; k < G_; ++k)
            out[obase + k * 49] = accs[k];
    }
}

// Shared prologue: returns false if this block's roi belongs to the other class.
__device__ __forceinline__ bool main_prologue(
    const int* __restrict__ hdr, const int4* __restrict__ meta,
    int lane, int bidx, bool bigclass,
    int& srcbase, int& cols4, float& recip, int& T, int& nIter,
    int (&off)[16], float (&wt)[16], int& obase) {

    int r  = bidx >> 5;           // roi (roi-major: consecutive blocks share roi)
    int c0 = (bidx & 31) << 3;    // first of 8 contiguous channels

    const int* h = hdr + (r << 3);   // uniform -> s_load
    T = h[3];
    if ((T > TSPLIT_) != bigclass) return false;

    // Meta loads (long latency).
    int4 m[4];
#pragma unroll
    for (int s = 0; s < 4; ++s)
        m[s] = meta[(((r << 2) + s) << 6) + lane];

    int   rel_off = h[0];
    int   bi      = h[1];
    cols4 = h[2];
    recip = __int_as_float(h[4]);
    nIter = __builtin_amdgcn_readfirstlane(h[5]);

#pragma unroll
    for (int s = 0; s < 4; ++s) {
        unsigned int d0 = (unsigned int)m[s].x;
        unsigned int d1 = (unsigned int)m[s].y;
        int rlo = (int)(d0 & 0xffffu), rhi = (int)(d0 >> 16);
        int clo = (int)(d1 & 0xffffu), chi = (int)(d1 >> 16);
        off[4*s+0] = rlo + clo;
        off[4*s+1] = rlo + chi;
        off[4*s+2] = rhi + clo;
        off[4*s+3] = rhi + chi;
        unsigned int d2 = (unsigned int)m[s].z;
        unsigned int d3 = (unsigned int)m[s].w;
        wt[4*s+0] = h2f_lo(d2);
        wt[4*s+1] = h2f_hi(d2);
        wt[4*s+2] = h2f_lo(d3);
        wt[4*s+3] = h2f_hi(d3);
    }

    srcbase = (bi * C_ + c0) * HW_ + rel_off;
    obase   = (r * C_ + c0) * 49 + lane;
    return true;
}

// Class A: T <= 1024 (nIter 1..4), 8 KB LDS -> high occupancy.
__global__ __launch_bounds__(64) void roialign_mainA(
    const float* __restrict__ input, const int* __restrict__ hdr,
    const int4* __restrict__ meta, float* __restrict__ out) {
    __shared__ float lds[2][TSPLIT_];
    int lane = threadIdx.x;
    int srcbase, cols4, T, nIter, obase;
    float recip;
    int off[16]; float wt[16];
    if (!main_prologue(hdr, meta, lane, blockIdx.x, false,
                       srcbase, cols4, recip, T, nIter, off, wt, obase)) return;
    switch (nIter) {
        case 1: body<1>(input, out, lds[0], lds[1], lane, srcbase, cols4, recip, T, off, wt, obase); break;
        case 2: body<2>(input, out, lds[0], lds[1], lane, srcbase, cols4, recip, T, off, wt, obase); break;
        case 3: body<3>(input, out, lds[0], lds[1], lane, srcbase, cols4, recip, T, off, wt, obase); break;
        default: body<4>(input, out, lds[0], lds[1], lane, srcbase, cols4, recip, T, off, wt, obase); break;
    }
}

// Class B: T > 1024 (nIter 5..7), 12.8 KB LDS.
__global__ __launch_bounds__(64) void roialign_mainB(
    const float* __restrict__ input, const int* __restrict__ hdr,
    const int4* __restrict__ meta, float* __restrict__ out) {
    __shared__ float lds[2][1600];
    int lane = threadIdx.x;
    int srcbase, cols4, T, nIter, obase;
    float recip;
    int off[16]; float wt[16];
    if (!main_prologue(hdr, meta, lane, blockIdx.x, true,
                       srcbase, cols4, recip, T, nIter, off, wt, obase)) return;
    switch (nIter) {
        case 5: body<5>(input, out, lds[0], lds[1], lane, srcbase, cols4, recip, T, off, wt, obase); break;
        case 6: body<6>(input, out, lds[0], lds[1], lane, srcbase, cols4, recip, T, off, wt, obase); break;
        default: body<7>(input, out, lds[0], lds[1], lane, srcbase, cols4, recip, T, off, wt, obase); break;
    }
}

// ---------------- fallback (round-4 kernel, used if ws too small) ----------
#define RMAX_   41
#define STRIDE_ 42

__global__ __launch_bounds__(128) void roialign_fallback(
    const float* __restrict__ input,
    const float* __restrict__ rois,
    float* __restrict__ out) {
    __shared__ float lds[2][RMAX_ * STRIDE_];

    int lane = threadIdx.x & 63;
    int wv   = threadIdx.x >> 6;
    int bidx = blockIdx.x;
    int r = bidx >> 7;
    int c = ((bidx & 127) << 1) | wv;

    const float scale = 0.0625f;
    float bf = rois[r * 5 + 0];
    int   bi = (int)bf;
    float x1 = rois[r * 5 + 1] * scale;
    float y1 = rois[r * 5 + 2] * scale;
    float x2 = rois[r * 5 + 3] * scale;
    float y2 = rois[r * 5 + 4] * scale;
    float bin_w = fmaxf(x2 - x1, 1.0f) * (1.0f / 7.0f);
    float bin_h = fmaxf(y2 - y1, 1.0f) * (1.0f / 7.0f);

    int y0 = lo_clamped(sample_coord(y1, bin_h, 0, 0), H_);
    int x0 = lo_clamped(sample_coord(x1, bin_w, 0, 0), W_);
    int yE = min(lo_clamped(sample_coord(y1, bin_h, 6, 1), H_) + 1, H_ - 1);
    int xE = min(lo_clamped(sample_coord(x1, bin_w, 6, 1), W_) + 1, W_ - 1);
    int rows = min(yE - y0 + 1, RMAX_);
    int cols = min(xE - x0 + 1, RMAX_);

    const float* plane = input + ((size_t)bi * C_ + c) * HW_;
    float* myl = lds[wv];
    for (int rr = 0; rr < rows; ++rr) {
        lds_u32* dst = (lds_u32*)(myl + rr * STRIDE_);
        const float* src = plane + (y0 + rr) * W_ + x0 + lane;
        if (lane < cols)
            __builtin_amdgcn_global_load_lds((glb_u32*)src, dst, 4, 0, 0);
    }
    asm volatile("s_waitcnt vmcnt(0)" ::: "memory");
    __builtin_amdgcn_sched_barrier(0);

    if (lane < 49) {
        int ph = lane / 7;
        int pw = lane % 7;
        int   ry[2][2];
        float fy[2];
        bool  vy[2];
#pragma unroll
        for (int iy = 0; iy < 2; ++iy) {
            float y = sample_coord(y1, bin_h, ph, iy);
            vy[iy] = (y >= -1.0f) && (y <= (float)H_);
            float yc = fmaxf(y, 0.0f);
            float yl = floorf(yc);
            bool  edge = yl >= (float)(H_ - 1);
            int   lo = (int)fminf(yl, (float)(H_ - 1));
            int   hi = min(lo + 1, H_ - 1);
            fy[iy] = edge ? 0.0f : (yc - yl);
            ry[iy][0] = (lo - y0) * STRIDE_;
            ry[iy][1] = (hi - y0) * STRIDE_;
        }
        int   rxl[2], rxh[2];
        float fx[2];
        bool  vx[2];
#pragma unroll
        for (int ix = 0; ix < 2; ++ix) {
            float x = sample_coord(x1, bin_w, pw, ix);
            vx[ix] = (x >= -1.0f) && (x <= (float)W_);
            float xc = fmaxf(x, 0.0f);
            float xl = floorf(xc);
            bool  edge = xl >= (float)(W_ - 1);
            int   lo = (int)fminf(xl, (float)(W_ - 1));
            int   hi = min(lo + 1, W_ - 1);
            fx[ix] = edge ? 0.0f : (xc - xl);
            rxl[ix] = lo - x0;
            rxh[ix] = hi - x0;
        }
        float acc = 0.0f;
#pragma unroll
        for (int iy = 0; iy < 2; ++iy) {
            float lyw = fy[iy], hyw = 1.0f - lyw;
#pragma unroll
            for (int ix = 0; ix < 2; ++ix) {
                float lxw = fx[ix], hxw = 1.0f - lxw;
                float msk = (vy[iy] && vx[ix]) ? 1.0f : 0.0f;
                float v1 = myl[ry[iy][0] + rxl[ix]];
                float v2 = myl[ry[iy][0] + rxh[ix]];
                float v3 = myl[ry[iy][1] + rxl[ix]];
                float v4 = myl[ry[iy][1] + rxh[ix]];
                acc += msk * (hyw * hxw * v1 + hyw * lxw * v2 +
                              lyw * hxw * v3 + lyw * lxw * v4);
            }
        }
        out[(r * C_ + c) * 49 + lane] = acc * 0.25f;
    }
}

extern "C" void kernel_launch(void* const* d_in, const int* in_sizes, int n_in,
                              void* d_out, int out_size, void* d_ws, size_t ws_size,
                              hipStream_t stream) {
    const float* input = (const float*)d_in[0];
    const float* rois  = (const float*)d_in[1];
    float* out = (float*)d_out;

    if (ws_size >= (size_t)WS_NEED_) {
        int*  hdr  = (int*)d_ws;
        int4* meta = (int4*)((char*)d_ws + HDR_BYTES_);
        roialign_meta<<<R_, 64, 0, stream>>>(rois, hdr, meta);
        roialign_mainA<<<R_ * 32, 64, 0, stream>>>(input, hdr, meta, out);
        roialign_mainB<<<R_ * 32, 64, 0, stream>>>(input, hdr, meta, out);
    } else {
        roialign_fallback<<<R_ * (C_ / 2), 128, 0, stream>>>(input, rois, out);
    }
}

// Round 10
// 48.421 us; speedup vs baseline: 1.3230x; 1.3230x over previous
//
#include <hip/hip_runtime.h>
#include <hip/hip_fp16.h>

// ROIAlign: input (B=2, C=256, H=200, W=200) f32, rois (R=512, 5) f32
// output (R, C, 7, 7) f32.  sampling_ratio = 2, spatial_scale = 0.0625.
//
// Round 10: round-6 pipeline (best: G=8, 2-buffer, counted vmcnt) + XCD
// spatial locality. A bitonic-sort kernel orders rois by (image, y-stripe,
// x-center) into 8 spatially-compact chunks of 64; main kernel maps
// xcd = bidx&7 -> chunk, roi varies fastest within the XCD. Overlapping
// rois become co-resident in one XCD's 4MB L2 -> duplicate region reads
// turn from ~400ns L3 hits into ~85ns L2 hits (latency is the limiter:
// fill rate == per-CU outstanding cap / latency).

#define B_  2
#define C_  256
#define H_  200
#define W_  200
#define R_  512
#define HW_ (H_ * W_)
#define TOTAL_ (B_ * C_ * HW_)
#define BUF_ 1600   // max region floats: rows<=40 x cols4<=40
#define G_   8      // channels per wave

#define HDR_BYTES_  (R_ * 8 * 4)              // 16384
#define META_BYTES_ (R_ * 4 * 64 * 16)        // 2097152
#define PERM_BYTES_ (R_ * 4)                  // 2048
#define WS_NEED_    (HDR_BYTES_ + META_BYTES_ + PERM_BYTES_)

typedef __attribute__((address_space(3))) unsigned int lds_u32;
typedef const __attribute__((address_space(1))) unsigned int glb_u32;

__device__ __forceinline__ float sample_coord(float start, float bin, int p, int i) {
    // Single definition shared by bounds and per-sample math: identical fp
    // rounding guarantees relative region indices stay in-bounds.
    return start + (float)p * bin + ((float)i + 0.5f) * bin * 0.5f;
}
__device__ __forceinline__ int lo_clamped(float v, int size) {
    return (int)fminf(floorf(fmaxf(v, 0.0f)), (float)(size - 1));
}
__device__ __forceinline__ unsigned int pack_h2(float a, float b) {
    unsigned short ua = __half_as_ushort(__float2half(a));
    unsigned short ub = __half_as_ushort(__float2half(b));
    return (unsigned int)ua | ((unsigned int)ub << 16);
}
__device__ __forceinline__ float h2f_lo(unsigned int u) {
    return __half2float(__ushort_as_half((unsigned short)(u & 0xffffu)));
}
__device__ __forceinline__ float h2f_hi(unsigned int u) {
    return __half2float(__ushort_as_half((unsigned short)(u >> 16)));
}

// ------- sort kernel: 1 block x 512 threads, bitonic over packed keys -------
// key = (image<<10) | (y_stripe<<8) | x_quant  -> 8 spatially-compact chunks
// of 64 rois (4 y-stripes x 2 images). Deterministic (idx in low bits).
__global__ __launch_bounds__(512) void roialign_sort(
    const float* __restrict__ rois, int* __restrict__ perm) {
    __shared__ unsigned int a[R_];
    int t = threadIdx.x;

    float bf = rois[t * 5 + 0];
    float cx = (rois[t * 5 + 1] + rois[t * 5 + 3]) * 0.5f * 0.0625f;
    float cy = (rois[t * 5 + 2] + rois[t * 5 + 4]) * 0.5f * 0.0625f;
    int bi = (int)bf;
    int ys = min(3, max(0, (int)(cy * (4.0f / 200.0f))));
    int xq = min(255, max(0, (int)(cx * (256.0f / 200.0f))));
    unsigned int key = ((unsigned int)bi << 10) | ((unsigned int)ys << 8) |
                       (unsigned int)xq;
    a[t] = (key << 9) | (unsigned int)t;
    __syncthreads();

    for (int k = 2; k <= R_; k <<= 1) {
        for (int j = k >> 1; j > 0; j >>= 1) {
            int ixj = t ^ j;
            if (ixj > t) {
                bool up = ((t & k) == 0);
                unsigned int av = a[t], bv = a[ixj];
                if ((av > bv) == up) { a[t] = bv; a[ixj] = av; }
            }
            __syncthreads();
        }
    }
    perm[t] = (int)(a[t] & 511u);
}

// ---------------- meta kernel: one 64-thread block per roi ----------------
__global__ __launch_bounds__(64) void roialign_meta(
    const float* __restrict__ rois, int* __restrict__ hdr, int4* __restrict__ meta) {
    int r = blockIdx.x;
    int lane = threadIdx.x;

    const float scale = 0.0625f;
    float bf = rois[r * 5 + 0];
    int   bi = (int)bf;
    float x1 = rois[r * 5 + 1] * scale;
    float y1 = rois[r * 5 + 2] * scale;
    float x2 = rois[r * 5 + 3] * scale;
    float y2 = rois[r * 5 + 4] * scale;
    float bin_w = fmaxf(x2 - x1, 1.0f) * (1.0f / 7.0f);
    float bin_h = fmaxf(y2 - y1, 1.0f) * (1.0f / 7.0f);

    int y0 = lo_clamped(sample_coord(y1, bin_h, 0, 0), H_);
    int yE = min(lo_clamped(sample_coord(y1, bin_h, 6, 1), H_) + 1, H_ - 1);
    int x0 = lo_clamped(sample_coord(x1, bin_w, 0, 0), W_);
    int xE = min(lo_clamped(sample_coord(x1, bin_w, 6, 1), W_) + 1, W_ - 1);
    int rows = yE - y0 + 1;
    int cols = xE - x0 + 1;
    int cols4 = (cols + 3) & ~3;
    if ((cols4 & 31) == 0) cols4 += 4;   // dodge 32-bank alignment
    int   T = rows * cols4;
    int   nIter = (T + 255) >> 8;
    float recip = 1.0f / (float)cols4;   // floor((e+0.5)*recip) == e/cols4 exactly

    if (lane == 0) {
        int* h = hdr + r * 8;
        h[0] = y0 * W_ + x0;
        h[1] = bi;
        h[2] = cols4;
        h[3] = T;
        h[4] = __float_as_int(recip);
        h[5] = nIter;
        h[6] = 0;
        h[7] = 0;
    }

    int4 o[4] = {{0,0,0,0},{0,0,0,0},{0,0,0,0},{0,0,0,0}};
    if (lane < 49) {
        int ph = lane / 7;
        int pw = lane % 7;

        int   rlo_b[2], rhi_b[2];
        float fy[2];
        bool  vy[2];
#pragma unroll
        for (int iy = 0; iy < 2; ++iy) {
            float y = sample_coord(y1, bin_h, ph, iy);
            vy[iy] = (y >= -1.0f) && (y <= (float)H_);
            float yc = fmaxf(y, 0.0f);
            float yl = floorf(yc);
            bool  edge = yl >= (float)(H_ - 1);
            int   lo = (int)fminf(yl, (float)(H_ - 1));
            int   hi = min(lo + 1, H_ - 1);
            fy[iy] = edge ? 0.0f : (yc - yl);
            rlo_b[iy] = (lo - y0) * cols4 * 4;   // LDS byte offset
            rhi_b[iy] = (hi - y0) * cols4 * 4;
        }
        int   clo_b[2], chi_b[2];
        float fx[2];
        bool  vx[2];
#pragma unroll
        for (int ix = 0; ix < 2; ++ix) {
            float x = sample_coord(x1, bin_w, pw, ix);
            vx[ix] = (x >= -1.0f) && (x <= (float)W_);
            float xc = fmaxf(x, 0.0f);
            float xl = floorf(xc);
            bool  edge = xl >= (float)(W_ - 1);
            int   lo = (int)fminf(xl, (float)(W_ - 1));
            int   hi = min(lo + 1, W_ - 1);
            fx[ix] = edge ? 0.0f : (xc - xl);
            clo_b[ix] = (lo - x0) * 4;
            chi_b[ix] = (hi - x0) * 4;
        }
#pragma unroll
        for (int iy = 0; iy < 2; ++iy)
#pragma unroll
            for (int ix = 0; ix < 2; ++ix) {
                int s = iy * 2 + ix;
                float mk  = (vy[iy] && vx[ix]) ? 0.25f : 0.0f;  // mask * 1/(S*S)
                float wy0 = (1.0f - fy[iy]) * mk;
                float wy1 = fy[iy] * mk;
                float wx0 = 1.0f - fx[ix];
                float wx1 = fx[ix];
                o[s].x = rlo_b[iy] | (rhi_b[iy] << 16);
                o[s].y = clo_b[ix] | (chi_b[ix] << 16);
                o[s].z = (int)pack_h2(wy0, wy1);
                o[s].w = (int)pack_h2(wx0, wx1);
            }
    }
#pragma unroll
    for (int s = 0; s < 4; ++s)
        meta[((r * 4 + s) * 64) + lane] = o[s];
}

// ---------------- pipelined main kernel ----------------
template<int N> __device__ __forceinline__ void wait_vmcnt() {
    if constexpr (N == 0)      asm volatile("s_waitcnt vmcnt(0)" ::: "memory");
    else if constexpr (N == 1) asm volatile("s_waitcnt vmcnt(1)" ::: "memory");
    else if constexpr (N == 2) asm volatile("s_waitcnt vmcnt(2)" ::: "memory");
    else if constexpr (N == 3) asm volatile("s_waitcnt vmcnt(3)" ::: "memory");
    else if constexpr (N == 4) asm volatile("s_waitcnt vmcnt(4)" ::: "memory");
    else if constexpr (N == 5) asm volatile("s_waitcnt vmcnt(5)" ::: "memory");
    else if constexpr (N == 6) asm volatile("s_waitcnt vmcnt(6)" ::: "memory");
    else                       asm volatile("s_waitcnt vmcnt(7)" ::: "memory");
}

template<int NI>
__device__ __forceinline__ void body(
    const float* __restrict__ input, float* __restrict__ out,
    float* __restrict__ b0, float* __restrict__ b1,
    int lane, int srcbase, int cols4, float recip, int T,
    const int (&off)[16], const float (&wt)[16], int obase) {

    int e4 = lane << 2;

    // Per-lane staging offsets for the NI dwordx4 instructions (advance by
    // HW_ per channel). All indices compile-time after unroll -> registers.
    int so[NI];
#pragma unroll
    for (int i = 0; i < NI; ++i) {
        int e = e4 + (i << 8);
        int row = (int)(((float)e + 0.5f) * recip);
        int col = e - row * cols4;
        so[i] = srcbase + row * W_ + col;
    }

    auto STAGE = [&](float* bp) {
#pragma unroll
        for (int i = 0; i < NI; ++i) {
            if (e4 + (i << 8) < T) {                    // protect LDS buffer end
                int g = min(so[i], TOTAL_ - 4);         // tail-of-input safety
                __builtin_amdgcn_global_load_lds((glb_u32*)(input + g),
                                                 (lds_u32*)(bp + (i << 8)), 16, 0, 0);
            }
            so[i] += HW_;
        }
    };

    STAGE(b0);   // ch 0
    STAGE(b1);   // ch 1

    float accs[G_];
#pragma unroll
    for (int k = 0; k < G_; ++k) {
        // ch k's stage is the oldest NI loads; ch k+1's NI may stay in flight.
        if (k < G_ - 1) wait_vmcnt<NI>(); else wait_vmcnt<0>();
        float* bp = (k & 1) ? b1 : b0;
        const char* bb = (const char*)bp;
        float a = 0.0f;
#pragma unroll
        for (int s = 0; s < 4; ++s) {
            float v1 = *(const float*)(bb + off[4*s+0]);
            float v2 = *(const float*)(bb + off[4*s+1]);
            float v3 = *(const float*)(bb + off[4*s+2]);
            float v4 = *(const float*)(bb + off[4*s+3]);
            a += wt[4*s+0] * (wt[4*s+2] * v1 + wt[4*s+3] * v2)
               + wt[4*s+1] * (wt[4*s+2] * v3 + wt[4*s+3] * v4);
        }
        accs[k] = a;
        if (k < G_ - 2) {
            // All ds_reads from bp must have completed before overwriting it.
            asm volatile("s_waitcnt lgkmcnt(0)" ::: "memory");
            __builtin_amdgcn_sched_barrier(0);
            STAGE(bp);                                   // ch k+2, same buffer
        }
    }

    if (lane < 49) {
#pragma unroll
        for (int k = 0; k < G_; ++k)
            out[obase + k * 49] = accs[k];
    }
}

__global__ __launch_bounds__(64) void roialign_main(
    const float* __restrict__ input, const int* __restrict__ hdr,
    const int4* __restrict__ meta, const int* __restrict__ perm,
    float* __restrict__ out) {
    __shared__ float lds[2][BUF_];
    int lane = threadIdx.x;
    int bidx = blockIdx.x;

    // XCD-spatial mapping: blocks round-robin XCDs by bidx&7. XCD x owns the
    // 64 spatially-clustered rois perm[x*64..x*64+63]; roi varies fastest,
    // channel-group next, so the XCD's concurrent L2 working set is a few
    // channel planes of one spatial stripe.
    int xcd   = bidx & 7;
    int ixn   = bidx >> 3;
    int rank  = (xcd << 6) | (ixn & 63);
    int cg    = ixn >> 6;                 // 0..31
    int r     = perm[rank];               // uniform load
    int c0    = cg << 3;

    // Meta loads first (long latency, independent).
    int4 m[4];
#pragma unroll
    for (int s = 0; s < 4; ++s)
        m[s] = meta[(((r << 2) + s) << 6) + lane];

    const int* h = hdr + (r << 3);   // uniform -> s_load
    int   rel_off = h[0];
    int   bi      = h[1];
    int   cols4   = h[2];
    int   T       = h[3];
    float recip   = __int_as_float(h[4]);
    int   nIter   = __builtin_amdgcn_readfirstlane(h[5]);

    // Unpack sample tables once (shared by all 8 channels).
    int   off[16];
    float wt[16];
#pragma unroll
    for (int s = 0; s < 4; ++s) {
        unsigned int d0 = (unsigned int)m[s].x;
        unsigned int d1 = (unsigned int)m[s].y;
        int rlo = (int)(d0 & 0xffffu), rhi = (int)(d0 >> 16);
        int clo = (int)(d1 & 0xffffu), chi = (int)(d1 >> 16);
        off[4*s+0] = rlo + clo;
        off[4*s+1] = rlo + chi;
        off[4*s+2] = rhi + clo;
        off[4*s+3] = rhi + chi;
        unsigned int d2 = (unsigned int)m[s].z;
        unsigned int d3 = (unsigned int)m[s].w;
        wt[4*s+0] = h2f_lo(d2);
        wt[4*s+1] = h2f_hi(d2);
        wt[4*s+2] = h2f_lo(d3);
        wt[4*s+3] = h2f_hi(d3);
    }

    int srcbase = (bi * C_ + c0) * HW_ + rel_off;
    int obase   = (r * C_ + c0) * 49 + lane;

    switch (nIter) {
        case 1: body<1>(input, out, lds[0], lds[1], lane, srcbase, cols4, recip, T, off, wt, obase); break;
        case 2: body<2>(input, out, lds[0], lds[1], lane, srcbase, cols4, recip, T, off, wt, obase); break;
        case 3: body<3>(input, out, lds[0], lds[1], lane, srcbase, cols4, recip, T, off, wt, obase); break;
        case 4: body<4>(input, out, lds[0], lds[1], lane, srcbase, cols4, recip, T, off, wt, obase); break;
        case 5: body<5>(input, out, lds[0], lds[1], lane, srcbase, cols4, recip, T, off, wt, obase); break;
        case 6: body<6>(input, out, lds[0], lds[1], lane, srcbase, cols4, recip, T, off, wt, obase); break;
        default: body<7>(input, out, lds[0], lds[1], lane, srcbase, cols4, recip, T, off, wt, obase); break;
    }
}

// ---------------- fallback (round-4 kernel, used if ws too small) ----------
#define RMAX_   41
#define STRIDE_ 42

__global__ __launch_bounds__(128) void roialign_fallback(
    const float* __restrict__ input,
    const float* __restrict__ rois,
    float* __restrict__ out) {
    __shared__ float lds[2][RMAX_ * STRIDE_];

    int lane = threadIdx.x & 63;
    int wv   = threadIdx.x >> 6;
    int bidx = blockIdx.x;
    int r = bidx >> 7;
    int c = ((bidx & 127) << 1) | wv;

    const float scale = 0.0625f;
    float bf = rois[r * 5 + 0];
    int   bi = (int)bf;
    float x1 = rois[r * 5 + 1] * scale;
    float y1 = rois[r * 5 + 2] * scale;
    float x2 = rois[r * 5 + 3] * scale;
    float y2 = rois[r * 5 + 4] * scale;
    float bin_w = fmaxf(x2 - x1, 1.0f) * (1.0f / 7.0f);
    float bin_h = fmaxf(y2 - y1, 1.0f) * (1.0f / 7.0f);

    int y0 = lo_clamped(sample_coord(y1, bin_h, 0, 0), H_);
    int x0 = lo_clamped(sample_coord(x1, bin_w, 0, 0), W_);
    int yE = min(lo_clamped(sample_coord(y1, bin_h, 6, 1), H_) + 1, H_ - 1);
    int xE = min(lo_clamped(sample_coord(x1, bin_w, 6, 1), W_) + 1, W_ - 1);
    int rows = min(yE - y0 + 1, RMAX_);
    int cols = min(xE - x0 + 1, RMAX_);

    const float* plane = input + ((size_t)bi * C_ + c) * HW_;
    float* myl = lds[wv];
    for (int rr = 0; rr < rows; ++rr) {
        lds_u32* dst = (lds_u32*)(myl + rr * STRIDE_);
        const float* src = plane + (y0 + rr) * W_ + x0 + lane;
        if (lane < cols)
            __builtin_amdgcn_global_load_lds((glb_u32*)src, dst, 4, 0, 0);
    }
    asm volatile("s_waitcnt vmcnt(0)" ::: "memory");
    __builtin_amdgcn_sched_barrier(0);

    if (lane < 49) {
        int ph = lane / 7;
        int pw = lane % 7;
        int   ry[2][2];
        float fy[2];
        bool  vy[2];
#pragma unroll
        for (int iy = 0; iy < 2; ++iy) {
            float y = sample_coord(y1, bin_h, ph, iy);
            vy[iy] = (y >= -1.0f) && (y <= (float)H_);
            float yc = fmaxf(y, 0.0f);
            float yl = floorf(yc);
            bool  edge = yl >= (float)(H_ - 1);
            int   lo = (int)fminf(yl, (float)(H_ - 1));
            int   hi = min(lo + 1, H_ - 1);
            fy[iy] = edge ? 0.0f : (yc - yl);
            ry[iy][0] = (lo - y0) * STRIDE_;
            ry[iy][1] = (hi - y0) * STRIDE_;
        }
        int   rxl[2], rxh[2];
        float fx[2];
        bool  vx[2];
#pragma unroll
        for (int ix = 0; ix < 2; ++ix) {
            float x = sample_coord(x1, bin_w, pw, ix);
            vx[ix] = (x >= -1.0f) && (x <= (float)W_);
            float xc = fmaxf(x, 0.0f);
            float xl = floorf(xc);
            bool  edge = xl >= (float)(W_ - 1);
            int   lo = (int)fminf(xl, (float)(W_ - 1));
            int   hi = min(lo + 1, W_ - 1);
            fx[ix] = edge ? 0.0f : (xc - xl);
            rxl[ix] = lo - x0;
            rxh[ix] = hi - x0;
        }
        float acc = 0.0f;
#pragma unroll
        for (int iy = 0; iy < 2; ++iy) {
            float lyw = fy[iy], hyw = 1.0f - lyw;
#pragma unroll
            for (int ix = 0; ix < 2; ++ix) {
                float lxw = fx[ix], hxw = 1.0f - lxw;
                float msk = (vy[iy] && vx[ix]) ? 1.0f : 0.0f;
                float v1 = myl[ry[iy][0] + rxl[ix]];
                float v2 = myl[ry[iy][0] + rxh[ix]];
                float v3 = myl[ry[iy][1] + rxl[ix]];
                float v4 = myl[ry[iy][1] + rxh[ix]];
                acc += msk * (hyw * hxw * v1 + hyw * lxw * v2 +
                              lyw * hxw * v3 + lyw * lxw * v4);
            }
        }
        out[(r * C_ + c) * 49 + lane] = acc * 0.25f;
    }
}

extern "C" void kernel_launch(void* const* d_in, const int* in_sizes, int n_in,
                              void* d_out, int out_size, void* d_ws, size_t ws_size,
                              hipStream_t stream) {
    const float* input = (const float*)d_in[0];
    const float* rois  = (const float*)d_in[1];
    float* out = (float*)d_out;

    if (ws_size >= (size_t)WS_NEED_) {
        int*  hdr  = (int*)d_ws;
        int4* meta = (int4*)((char*)d_ws + HDR_BYTES_);
        int*  perm = (int*)((char*)d_ws + HDR_BYTES_ + META_BYTES_);
        roialign_sort<<<1, R_, 0, stream>>>(rois, perm);
        roialign_meta<<<R_, 64, 0, stream>>>(rois, hdr, meta);
        roialign_main<<<R_ * 32, 64, 0, stream>>>(input, hdr, meta, perm, out);
    } else {
        roialign_fallback<<<R_ * (C_ / 2), 128, 0, stream>>>(input, rois, out);
    }
}